// Round 15
// baseline (87.606 us; speedup 1.0000x reference)
//
#include <hip/hip_runtime.h>

// CRF loss: out[b] = logZ[b] - target[b].  B=256, S=2048, D=64.
// Round 15: r14 (86us, bf16 state + dot2) with ONE change: all f32->bf16
//   conversions use SOFTWARE round-to-nearest-even instead of
//   v_cvt_pk_bf16_f32 (suspected RTZ/truncating like v_cvt_pkrtz_f16 ->
//   systematic downward bias -> r5/r14's identical absmax=192).

#define B_   256
#define S_   2048
#define D_   64
#define CHK  32      // chunks per batch
#define CL   64      // accounted steps per chunk
#define WUP  8       // warmup steps
#define WPB  4       // waves per block

// ---------------- target scores: point + transition ----------------
__global__ __launch_bounds__(256) void target_kernel(
    const float* __restrict__ y_pred, const int* __restrict__ y_true,
    const float* __restrict__ mask, const float* __restrict__ trans,
    float* __restrict__ target)
{
    int b = blockIdx.x;
    int tid = threadIdx.x;
    const int*   yt = y_true + (size_t)b * S_;
    const float* mk = mask   + (size_t)b * S_;
    const float* yp = y_pred + (size_t)b * S_ * D_;

    float acc = 0.f;
    for (int n = tid; n < S_; n += 256) {
        int   tn = yt[n];
        float mn = mk[n];
        acc += mn * mn * yp[(size_t)n * D_ + tn];
        if (n + 1 < S_) {
            int   tn1 = yt[n + 1];
            float mn1 = mk[n + 1];
            acc += mn * mn1 * trans[tn * D_ + tn1];
        }
    }
    #pragma unroll
    for (int m = 32; m >= 1; m >>= 1) acc += __shfl_xor(acc, m, 64);
    __shared__ float sred[4];
    int wid = tid >> 6;
    if ((tid & 63) == 0) sred[wid] = acc;
    __syncthreads();
    if (tid == 0) target[b] = sred[0] + sred[1] + sred[2] + sred[3];
}

// f32 -> bf16 with round-to-nearest-even (software; provably unbiased)
static __device__ __forceinline__ unsigned bf16_rne(float x) {
    unsigned u = __float_as_uint(x);
    u += 0x7fffu + ((u >> 16) & 1u);
    return u >> 16;
}

// d = a.lo*b.lo + a.hi*b.hi + c   (bf16 pairs, f32 accumulate)
static __device__ __forceinline__ float dot2bf(unsigned a, unsigned b, float c) {
    float d;
    asm("v_dot2_f32_bf16 %0, %1, %2, %3" : "=v"(d) : "v"(a), "v"(b), "v"(c));
    return d;
}

// ---------------- chunked forward scan: 4 chunk-waves per block ------------
__global__ __launch_bounds__(256) void chunk_scan_kernel(
    const float* __restrict__ y_pred, const float* __restrict__ mask,
    const float* __restrict__ trans, float* __restrict__ partials)
{
    const int wid = threadIdx.x >> 6;
    const int j   = threadIdx.x & 63;     // lane = state index
    const int idx = blockIdx.x * WPB + wid;
    const int b = idx >> 5;               // batch
    const int c = idx & (CHK - 1);        // chunk
    const float* yprow = y_pred + (size_t)b * S_ * D_;
    const float* mrow  = mask   + (size_t)b * S_;

    // ET column j as bf16 pairs (rne): etw[q] = { exp(T[2q][j]), exp(T[2q+1][j]) }
    unsigned etw[32];
    #pragma unroll
    for (int q = 0; q < 32; ++q) {
        float e0 = __expf(trans[(2 * q + 0) * D_ + j]);
        float e1 = __expf(trans[(2 * q + 1) * D_ + j]);
        etw[q] = bf16_rne(e0) | (bf16_rne(e1) << 16);
    }

    // per-wave private bf16 broadcast slice (128 B); single wave owns it ->
    // in-order DS pipe, no barriers (disjoint across waves)
    __shared__ uint4 spq[WPB][8];
    uint4* myq = spq[wid];
    unsigned short* myh = (unsigned short*)myq;

    float p = (c == 0) ? __expf(yprow[j] * mrow[0]) : 1.0f;
    int   K = 0;        // exact pow2 offset (log magnitude += K*ln2)
    float Of = 0.f;     // masked-path log offset
    myh[j] = (unsigned short)bf16_rne(p);

    auto mag = [&]() -> double {
        float fs = p;
        #pragma unroll
        for (int m = 1; m <= 32; m <<= 1) fs += __shfl_xor(fs, m, 64);
        return (double)K * 0.6931471805599453 + (double)Of + (double)__logf(fs);
    };
    double m_start = 0.0;   // chunk 0 reports ABSOLUTE m(t=CL)

    auto step = [&](float eraw, float exs, float cs, bool dorescale) {
        // matvec: sum_j = sum_i p_i(bf16) * ET[i][j](bf16), f32 accumulate
        const uint4* pb = myq;
        float a0 = 0.f, a1 = 0.f, a2 = 0.f, a3 = 0.f;
        #pragma unroll
        for (int u = 0; u < 8; ++u) {
            uint4 w = pb[u];
            a0 = dot2bf(w.x, etw[4 * u + 0], a0);
            a1 = dot2bf(w.y, etw[4 * u + 1], a1);
            a2 = dot2bf(w.z, etw[4 * u + 2], a2);
            a3 = dot2bf(w.w, etw[4 * u + 3], a3);
        }
        float sum = (a0 + a1) + (a2 + a3);

        if (cs == 1.0f) {
            p = sum * exs;
        } else {
            // masked path: exact for cm in {0,1} (r3-proven structure)
            float sj   = __logf(p);
            float outn = __logf(sum) + eraw * cs;
            float ns   = cs * outn + (1.f - cs) * sj;
            float M = ns;
            #pragma unroll
            for (int m = 1; m <= 32; m <<= 1) M = fmaxf(M, __shfl_xor(M, m, 64));
            p = __expf(ns - M);
            Of += M;
        }
        if (dorescale) {
            unsigned pb0 = __builtin_amdgcn_readfirstlane(__float_as_uint(p));
            int k = (int)((pb0 >> 23) & 0xffu) - 127;
            k = k < -110 ? -110 : (k > 110 ? 110 : k);
            float sc = __uint_as_float((unsigned)(127 - k) << 23);  // exact 2^-k
            p *= sc;
            K += k;
        }
        myh[j] = (unsigned short)bf16_rne(p);
    };

    // groups of 4 steps; every group starts at t === 1 (mod 4) -> renorm at s=3.
    // c==0: 16 groups (t=1..64, no warmup, m_start=0)
    // c>0 : 18 groups (2 warmup groups t=64c-7..64c, then 16 accounted)
    const int t0      = (c == 0) ? 1 : CL * c - (WUP - 1);
    const int ngrp    = (c == 0) ? 16 : 18;
    const int rec_grp = (c == 0) ? -1 : 1;   // record m_start after this group
    const bool lastch = (c == CHK - 1);      // chunk 31: final step t=2048 skipped

    float e_nxt[4], c_nxt[4], e_cur[4], c_cur[4], ex[4];
    #pragma unroll
    for (int s = 0; s < 4; ++s) {
        int t = t0 + s; if (t > S_ - 1) t = S_ - 1;
        e_nxt[s] = yprow[(size_t)t * D_ + j];
        c_nxt[s] = mrow[t];
    }

    for (int grp = 0; grp < ngrp; ++grp) {
        #pragma unroll
        for (int s = 0; s < 4; ++s) { e_cur[s] = e_nxt[s]; c_cur[s] = c_nxt[s]; }
        const int tb = t0 + 4 * (grp + 1);
        #pragma unroll
        for (int s = 0; s < 4; ++s) {
            int t = tb + s; if (t > S_ - 1) t = S_ - 1;
            e_nxt[s] = yprow[(size_t)t * D_ + j];
            c_nxt[s] = mrow[t];
        }
        #pragma unroll
        for (int s = 0; s < 4; ++s) ex[s] = __expf(e_cur[s]);

        step(e_cur[0], ex[0], c_cur[0], false);
        step(e_cur[1], ex[1], c_cur[1], false);
        step(e_cur[2], ex[2], c_cur[2], false);
        if (!(lastch && grp == ngrp - 1))          // skip only t=2048
            step(e_cur[3], ex[3], c_cur[3], true); // renorm every 4th step
        if (grp == rec_grp) m_start = mag();       // end of warmup
    }

    double delta = mag() - m_start;
    if (j == 0) partials[(size_t)b * CHK + c] = (float)delta;
}

// ---------------- combine: out[b] = sum_c delta[b][c] - target[b] ----------
__global__ __launch_bounds__(256) void combine_kernel(
    const float* __restrict__ partials, const float* __restrict__ target,
    float* __restrict__ out)
{
    int b = blockIdx.x * 256 + threadIdx.x;
    if (b >= B_) return;
    double acc = 0.0;
    #pragma unroll
    for (int c = 0; c < CHK; ++c) acc += (double)partials[(size_t)b * CHK + c];
    out[b] = (float)acc - target[b];
}

extern "C" void kernel_launch(void* const* d_in, const int* in_sizes, int n_in,
                              void* d_out, int out_size, void* d_ws, size_t ws_size,
                              hipStream_t stream)
{
    const float* y_pred = (const float*)d_in[0];
    const int*   y_true = (const int*)d_in[1];
    const float* mask   = (const float*)d_in[2];
    const float* trans  = (const float*)d_in[3];
    float* outp     = (float*)d_out;
    float* target   = (float*)d_ws;                       // 256 f
    float* partials = (float*)((char*)d_ws + 4096);       // 256*32 f

    hipLaunchKernelGGL(target_kernel, dim3(B_), dim3(256), 0, stream,
                       y_pred, y_true, mask, trans, target);
    hipLaunchKernelGGL(chunk_scan_kernel, dim3(B_ * CHK / WPB), dim3(256), 0,
                       stream, y_pred, mask, trans, partials);
    hipLaunchKernelGGL(combine_kernel, dim3(1), dim3(256), 0, stream,
                       partials, target, outp);
}

// Round 16
// 64.818 us; speedup vs baseline: 1.3516x; 1.3516x over previous
//
#include <hip/hip_runtime.h>

// CRF loss: out[b] = logZ[b] - target[b].  B=256, S=2048, D=64.
// Round 16: chunked MFMA scan. 16 batches/wave via mfma_f32_16x16x16_bf16
//   (r5-verified fragment layout), RNE bf16 packing (r15-verified fix),
//   CL=16/WUP=8 chunks -> 2048 single-wave blocks, wave-uniform clamped
//   pow2 renorm (safe: drift over 24 steps << fp32 range), no LDS.

#define B_   256
#define S_   2048
#define D_   64
#define CHK  128     // chunks per batch
#define CL   16      // accounted steps per chunk
#define WUP  8       // warmup steps

typedef float  f32x4 __attribute__((ext_vector_type(4)));
typedef short  v4s   __attribute__((ext_vector_type(4)));

#if __has_builtin(__builtin_amdgcn_mfma_f32_16x16x16bf16_1k)
static __device__ __forceinline__ f32x4 mfma16(v4s a, v4s b, f32x4 cc) {
    return __builtin_amdgcn_mfma_f32_16x16x16bf16_1k(a, b, cc, 0, 0, 0);
}
#else
static __device__ __forceinline__ f32x4 mfma16(v4s a, v4s b, f32x4 cc) {
    f32x4 d;
    asm("v_mfma_f32_16x16x16_bf16 %0, %1, %2, %3"
        : "=&v"(d) : "v"(a), "v"(b), "v"(cc));
    return d;
}
#endif

// f32 -> bf16 round-to-nearest-even (r15-verified; v_cvt_pk_bf16_f32 truncates)
static __device__ __forceinline__ unsigned bf16_rne(float x) {
    unsigned u = __float_as_uint(x);
    u += 0x7fffu + ((u >> 16) & 1u);
    return u >> 16;
}
static __device__ __forceinline__ float bf2f(short h) {
    return __uint_as_float(((unsigned)(unsigned short)h) << 16);
}
static __device__ __forceinline__ v4s pack4(float a, float b, float c2, float d) {
    union { uint2 u; v4s s; } uu;
    uu.u.x = bf16_rne(a) | (bf16_rne(b) << 16);
    uu.u.y = bf16_rne(c2) | (bf16_rne(d) << 16);
    return uu.s;
}

// ---------------- target scores: point + transition ----------------
__global__ __launch_bounds__(256) void target_kernel(
    const float* __restrict__ y_pred, const int* __restrict__ y_true,
    const float* __restrict__ mask, const float* __restrict__ trans,
    float* __restrict__ target)
{
    int b = blockIdx.x;
    int tid = threadIdx.x;
    const int*   yt = y_true + (size_t)b * S_;
    const float* mk = mask   + (size_t)b * S_;
    const float* yp = y_pred + (size_t)b * S_ * D_;

    float acc = 0.f;
    for (int n = tid; n < S_; n += 256) {
        int   tn = yt[n];
        float mn = mk[n];
        acc += mn * mn * yp[(size_t)n * D_ + tn];
        if (n + 1 < S_) {
            int   tn1 = yt[n + 1];
            float mn1 = mk[n + 1];
            acc += mn * mn1 * trans[tn * D_ + tn1];
        }
    }
    #pragma unroll
    for (int m = 32; m >= 1; m >>= 1) acc += __shfl_xor(acc, m, 64);
    __shared__ float sred[4];
    int wid = tid >> 6;
    if ((tid & 63) == 0) sred[wid] = acc;
    __syncthreads();
    if (tid == 0) target[b] = sred[0] + sred[1] + sred[2] + sred[3];
}

// ---------------- chunked MFMA forward scan ----------------
// wave u: batch group bg = u&15 (16 batches), chunk c = u>>4.
__global__ __launch_bounds__(64, 2) void mfma_chunk_scan(
    const float* __restrict__ y_pred, const float* __restrict__ mask,
    const float* __restrict__ trans, float* __restrict__ partials)
{
    const int u  = blockIdx.x;
    const int bg = u & 15;
    const int c  = u >> 4;
    const int l  = threadIdx.x;
    const int g  = l >> 4, cb = l & 15;   // g = k/row quad, cb = batch-in-group
    const int b0 = bg * 16;
    const float* yprowc = y_pred + (size_t)(b0 + cb) * S_ * D_;
    const float* mrowc  = mask   + (size_t)(b0 + cb) * S_;

    // A fragments (r5-verified layout): Av[m][kt] elem e =
    //   exp(trans[16kt+4g+e][16m+cb])   (= ET^T tile (m,kt))
    v4s Av[4][4];
    #pragma unroll
    for (int m = 0; m < 4; ++m)
        #pragma unroll
        for (int kt = 0; kt < 4; ++kt) {
            float a0 = __expf(trans[(16*kt + 4*g + 0) * D_ + 16*m + cb]);
            float a1 = __expf(trans[(16*kt + 4*g + 1) * D_ + 16*m + cb]);
            float a2 = __expf(trans[(16*kt + 4*g + 2) * D_ + 16*m + cb]);
            float a3 = __expf(trans[(16*kt + 4*g + 3) * D_ + 16*m + cb]);
            Av[m][kt] = pack4(a0, a1, a2, a3);
        }

    // state B fragments: Bv[kt] elem e = p[state 16kt+4g+e][batch cb]
    v4s Bv[4];
    if (c == 0) {
        float m0 = mrowc[0];
        #pragma unroll
        for (int kt = 0; kt < 4; ++kt) {
            float p0 = __expf(yprowc[16*kt + 4*g + 0] * m0);
            float p1 = __expf(yprowc[16*kt + 4*g + 1] * m0);
            float p2 = __expf(yprowc[16*kt + 4*g + 2] * m0);
            float p3 = __expf(yprowc[16*kt + 4*g + 3] * m0);
            Bv[kt] = pack4(p0, p1, p2, p3);
        }
    } else {
        const short one = (short)0x3f80;          // bf16(1.0)
        v4s vone = {one, one, one, one};
        #pragma unroll
        for (int kt = 0; kt < 4; ++kt) Bv[kt] = vone;
    }

    int K = 0;                 // wave-uniform exact pow2 offset
    const f32x4 zf = {0.f, 0.f, 0.f, 0.f};

    // per-batch magnitude: log(sum of 16 states this lane) summed across the
    // batch's 4 lanes via symmetric xor tree, + K*ln2
    auto mag = [&]() -> double {
        float s = 0.f;
        #pragma unroll
        for (int m = 0; m < 4; ++m)
            s += (bf2f(Bv[m][0]) + bf2f(Bv[m][1])) +
                 (bf2f(Bv[m][2]) + bf2f(Bv[m][3]));
        s += __shfl_xor(s, 16, 64);
        s += __shfl_xor(s, 32, 64);
        return (double)K * 0.6931471805599453 + (double)__logf(s);
    };

    const int t0    = (c == 0) ? 1 : CL * c - (WUP - 1);
    const int t_end = (CL * (c + 1) > S_ - 1) ? (S_ - 1) : CL * (c + 1);
    const int rec_t = CL * c;          // c>0: record m_start after this step
    double m_start = 0.0;

    // one step at time t; E[m] = y_pred[b0+cb][t][16m+4g .. +3], cm = mask
    auto step = [&](int t, float4 e0, float4 e1, float4 e2, float4 e3, float cm) {
        f32x4 acc[4];
        #pragma unroll
        for (int m = 0; m < 4; ++m) acc[m] = mfma16(Av[m][0], Bv[0], zf);
        #pragma unroll
        for (int kt = 1; kt < 4; ++kt)
            #pragma unroll
            for (int m = 0; m < 4; ++m)
                acc[m] = mfma16(Av[m][kt], Bv[kt], acc[m]);

        float4 ee[4] = {e0, e1, e2, e3};
        f32x4 pr[4];
        if (__builtin_expect(__all(cm == 1.0f), 1)) {
            #pragma unroll
            for (int m = 0; m < 4; ++m) {
                pr[m][0] = acc[m][0] * __expf(ee[m].x);
                pr[m][1] = acc[m][1] * __expf(ee[m].y);
                pr[m][2] = acc[m][2] * __expf(ee[m].z);
                pr[m][3] = acc[m][3] * __expf(ee[m].w);
            }
        } else {
            // masked path: exact for cm in {0,1}; log-blend for fractional
            #pragma unroll
            for (int m = 0; m < 4; ++m) {
                float er[4] = {ee[m].x, ee[m].y, ee[m].z, ee[m].w};
                #pragma unroll
                for (int e = 0; e < 4; ++e) {
                    float sum  = acc[m][e];
                    float pold = bf2f(Bv[m][e]);
                    float pn;
                    if (cm == 1.0f) {
                        pn = sum * __expf(er[e]);
                    } else {
                        float outn = __logf(sum) + er[e] * cm;
                        float oldl = __logf(pold);
                        pn = __expf(cm * outn + (1.f - cm) * oldl);
                    }
                    pr[m][e] = pn;
                }
            }
        }

        if ((t & 3) == 0) {   // wave-uniform exact pow2 renorm (clamped)
            unsigned rep = __builtin_amdgcn_readfirstlane(__float_as_uint(pr[0][0]));
            int k = (int)((rep >> 23) & 0xffu) - 127;
            k = k < -110 ? -110 : (k > 110 ? 110 : k);
            float sc = __uint_as_float((unsigned)(127 - k) << 23);
            #pragma unroll
            for (int m = 0; m < 4; ++m) {
                pr[m][0] *= sc; pr[m][1] *= sc; pr[m][2] *= sc; pr[m][3] *= sc;
            }
            K += k;
        }

        #pragma unroll
        for (int m = 0; m < 4; ++m)
            Bv[m] = pack4(pr[m][0], pr[m][1], pr[m][2], pr[m][3]);

        if (c > 0 && t == rec_t) m_start = mag();
    };

    // 2-deep ping-pong prefetch of e rows (4 x dwordx4) + cm, static rotation
    float4 EA0, EA1, EA2, EA3, EB0, EB1, EB2, EB3;
    float  cmA, cmB;
    auto loadA = [&](int t) {
        int tt = t > t_end ? t_end : t;
        const float* base = yprowc + (size_t)tt * D_ + 4 * g;
        EA0 = *(const float4*)(base +  0); EA1 = *(const float4*)(base + 16);
        EA2 = *(const float4*)(base + 32); EA3 = *(const float4*)(base + 48);
        cmA = mrowc[tt];
    };
    auto loadB = [&](int t) {
        int tt = t > t_end ? t_end : t;
        const float* base = yprowc + (size_t)tt * D_ + 4 * g;
        EB0 = *(const float4*)(base +  0); EB1 = *(const float4*)(base + 16);
        EB2 = *(const float4*)(base + 32); EB3 = *(const float4*)(base + 48);
        cmB = mrowc[tt];
    };

    loadA(t0); loadB(t0 + 1);
    for (int t = t0; t <= t_end; t += 2) {
        {
            float4 e0 = EA0, e1 = EA1, e2 = EA2, e3 = EA3; float cm = cmA;
            loadA(t + 2);
            step(t, e0, e1, e2, e3, cm);
        }
        if (t + 1 <= t_end) {
            float4 e0 = EB0, e1 = EB1, e2 = EB2, e3 = EB3; float cm = cmB;
            loadB(t + 3);
            step(t + 1, e0, e1, e2, e3, cm);
        }
    }

    double delta = mag() - m_start;
    if (l < 16) partials[(size_t)(b0 + l) * CHK + c] = (float)delta;
}

// ---------------- combine: out[b] = sum_c delta[b][c] - target[b] ----------
__global__ __launch_bounds__(256) void combine_kernel(
    const float* __restrict__ partials, const float* __restrict__ target,
    float* __restrict__ out)
{
    int b = blockIdx.x * 256 + threadIdx.x;
    if (b >= B_) return;
    double acc = 0.0;
    for (int c = 0; c < CHK; ++c) acc += (double)partials[(size_t)b * CHK + c];
    out[b] = (float)acc - target[b];
}

extern "C" void kernel_launch(void* const* d_in, const int* in_sizes, int n_in,
                              void* d_out, int out_size, void* d_ws, size_t ws_size,
                              hipStream_t stream)
{
    const float* y_pred = (const float*)d_in[0];
    const int*   y_true = (const int*)d_in[1];
    const float* mask   = (const float*)d_in[2];
    const float* trans  = (const float*)d_in[3];
    float* outp     = (float*)d_out;
    float* target   = (float*)d_ws;                       // 256 f
    float* partials = (float*)((char*)d_ws + 4096);       // 256*128 f

    hipLaunchKernelGGL(target_kernel, dim3(B_), dim3(256), 0, stream,
                       y_pred, y_true, mask, trans, target);
    hipLaunchKernelGGL(mfma_chunk_scan, dim3(16 * CHK), dim3(64), 0, stream,
                       y_pred, mask, trans, partials);
    hipLaunchKernelGGL(combine_kernel, dim3(1), dim3(256), 0, stream,
                       partials, target, outp);
}